// Round 1
// baseline (200.332 us; speedup 1.0000x reference)
//
#include <hip/hip_runtime.h>
#include <math.h>

#define PAD 33      // LDS stride for H: conflict-free rows AND columns
#define NBT 25      // reference MAX_BT

__device__ __forceinline__ float hsum4(float4 v) { return (v.x + v.y) + (v.z + v.w); }

__global__ __launch_bounds__(256, 4) void bfgs_kernel(
    const float* __restrict__ y_g,
    const float* __restrict__ h_g,
    const int*   __restrict__ iter_g,
    float*       __restrict__ out)
{
    // per block: 8 problems, one per 32-lane half-wave
    __shared__ __align__(16) float Hs[8][32 * PAD];   // 8 * 4224 B = 33792 B
    __shared__ __align__(16) float vs[8][4][32];      // slots: 0=p/s 1=q 2=t 3=hy (4096 B)

    const int tid  = threadIdx.x;
    const int l    = tid & 31;          // lane within problem
    const int pp   = tid >> 5;          // problem within block
    const int prob = blockIdx.x * 8 + pp;
    const int sh   = tid & 32;          // ballot shift for this half-wave

    const float* __restrict__ hb = h_g + (size_t)prob * 1024;
    float* Hp = Hs[pp];
    float* sP = vs[pp][0];
    float* sQ = vs[pp][1];
    float* sT = vs[pp][2];
    float* sH = vs[pp][3];

    // ---- stage H (row-major) into padded LDS, coalesced float4 global reads ----
    #pragma unroll
    for (int u = 0; u < 8; ++u) {
        const int f = u * 128 + l * 4;
        const float4 v = *reinterpret_cast<const float4*>(hb + f);
        const int r = f >> 5, c = f & 31;
        float* d = Hp + r * PAD + c;
        d[0] = v.x; d[1] = v.y; d[2] = v.z; d[3] = v.w;
    }
    const float yv = y_g[prob * 32 + l];
    sP[l] = yv;
    __builtin_amdgcn_wave_barrier();

    // ---- b = H^T y (distributed), c0 = y.y (replicated) ----
    float4 bacc = {0.f,0.f,0.f,0.f};
    float4 cacc = {0.f,0.f,0.f,0.f};
    #pragma unroll
    for (int k4 = 0; k4 < 8; ++k4) {
        const float4 y4 = *reinterpret_cast<const float4*>(sP + 4 * k4);
        bacc.x = fmaf(Hp[(4*k4+0)*PAD + l], y4.x, bacc.x);
        bacc.y = fmaf(Hp[(4*k4+1)*PAD + l], y4.y, bacc.y);
        bacc.z = fmaf(Hp[(4*k4+2)*PAD + l], y4.z, bacc.z);
        bacc.w = fmaf(Hp[(4*k4+3)*PAD + l], y4.w, bacc.w);
        cacc.x = fmaf(y4.x, y4.x, cacc.x);
        cacc.y = fmaf(y4.y, y4.y, cacc.y);
        cacc.z = fmaf(y4.z, y4.z, cacc.z);
        cacc.w = fmaf(y4.w, y4.w, cacc.w);
    }
    const float b_l = hsum4(bacc);
    const float c0  = hsum4(cacc);

    // allgather b -> replicated g = -b  (x0 = 0)
    sT[l] = b_l;
    __builtin_amdgcn_wave_barrier();
    float g[32];
    #pragma unroll
    for (int k4 = 0; k4 < 8; ++k4) {
        const float4 b4 = *reinterpret_cast<const float4*>(sT + 4 * k4);
        g[4*k4+0] = -b4.x; g[4*k4+1] = -b4.y; g[4*k4+2] = -b4.z; g[4*k4+3] = -b4.w;
    }

    float hk[32];                        // row l of h_k, identity init
    #pragma unroll
    for (int j = 0; j < 32; ++j) hk[j] = (j == l) ? 1.0f : 0.0f;

    float x_l = 0.0f, alpha = 1.0f, rr = c0;   // rr = ||y - H x||^2
    const int niter = iter_g[0];

    for (int it = 0; it < niter; ++it) {
        // ---- p = -(h_k @ g), all-register ----
        float4 pa = {0.f,0.f,0.f,0.f};
        #pragma unroll
        for (int k4 = 0; k4 < 8; ++k4) {
            pa.x = fmaf(hk[4*k4+0], g[4*k4+0], pa.x);
            pa.y = fmaf(hk[4*k4+1], g[4*k4+1], pa.y);
            pa.z = fmaf(hk[4*k4+2], g[4*k4+2], pa.z);
            pa.w = fmaf(hk[4*k4+3], g[4*k4+3], pa.w);
        }
        const float p_l = -hsum4(pa);
        sP[l] = p_l;
        __builtin_amdgcn_wave_barrier();

        // ---- gp = g.p (replicated) ; q_l = (H p)_l via row-l reads ----
        float4 ga = {0.f,0.f,0.f,0.f};
        float4 qa = {0.f,0.f,0.f,0.f};
        #pragma unroll
        for (int k4 = 0; k4 < 8; ++k4) {
            const float4 p4 = *reinterpret_cast<const float4*>(sP + 4 * k4);
            ga.x = fmaf(g[4*k4+0], p4.x, ga.x);
            ga.y = fmaf(g[4*k4+1], p4.y, ga.y);
            ga.z = fmaf(g[4*k4+2], p4.z, ga.z);
            ga.w = fmaf(g[4*k4+3], p4.w, ga.w);
            qa.x = fmaf(Hp[l*PAD + 4*k4+0], p4.x, qa.x);
            qa.y = fmaf(Hp[l*PAD + 4*k4+1], p4.y, qa.y);
            qa.z = fmaf(Hp[l*PAD + 4*k4+2], p4.z, qa.z);
            qa.w = fmaf(Hp[l*PAD + 4*k4+3], p4.w, qa.w);
        }
        const float gp  = hsum4(ga);
        const float q_l = hsum4(qa);
        sQ[l] = q_l;
        __builtin_amdgcn_wave_barrier();

        // ---- t_l = (H^T q)_l via column-l reads ; qq = q.q (replicated) ----
        float4 ta  = {0.f,0.f,0.f,0.f};
        float4 qqa = {0.f,0.f,0.f,0.f};
        #pragma unroll
        for (int k4 = 0; k4 < 8; ++k4) {
            const float4 q4 = *reinterpret_cast<const float4*>(sQ + 4 * k4);
            ta.x = fmaf(Hp[(4*k4+0)*PAD + l], q4.x, ta.x);
            ta.y = fmaf(Hp[(4*k4+1)*PAD + l], q4.y, ta.y);
            ta.z = fmaf(Hp[(4*k4+2)*PAD + l], q4.z, ta.z);
            ta.w = fmaf(Hp[(4*k4+3)*PAD + l], q4.w, ta.w);
            qqa.x = fmaf(q4.x, q4.x, qqa.x);
            qqa.y = fmaf(q4.y, q4.y, qqa.y);
            qqa.z = fmaf(q4.z, q4.z, qqa.z);
            qqa.w = fmaf(q4.w, q4.w, qqa.w);
        }
        const float t_l = hsum4(ta);
        const float qq  = hsum4(qqa);

        // ---- Armijo backtracking, ballot-parallel over candidate alphas ----
        // phi(a) = ||r - a q||^2 = rr - 2 a rq + a^2 qq,  rq = r.q = -g.p
        // cond(a) = f(x+ap) > fx + C a gp  <=>  rhs<0 || phi/4 > rhs^2
        const float rq = -gp;
        const float fx = 0.5f * sqrtf(rr);
        const float a_c = ldexpf(alpha, -l);            // exact: alpha * 2^-l
        const float rhs = fx + (1e-4f * a_c) * gp;
        const float phi_c = fmaf(a_c, fmaf(a_c, qq, -2.0f * rq), rr);
        const bool cond = (rhs < 0.0f) || (0.25f * phi_c > rhs * rhs);
        const unsigned long long bal = __ballot(cond);
        const unsigned mh  = (unsigned)(bal >> sh);
        const unsigned inv = (~mh & 0x01FFFFFFu) | 0x02000000u; // first false idx, cap 25
        const int kk = __ffs(inv) - 1;
        alpha = ldexpf(alpha, -kk);

        // ---- x update; s with the reference's rounding (x_new - x) ----
        const float xn  = fmaf(alpha, p_l, x_l);
        const float s_l = xn - x_l;
        x_l = xn;
        rr = fmaf(alpha, fmaf(alpha, qq, -2.0f * rq), rr);   // rr at accepted alpha

        sP[l] = s_l;     // overwrite p slot (p fully consumed)
        sT[l] = t_l;
        __builtin_amdgcn_wave_barrier();

        // ---- fused: g += alpha*t ; hy_l = (h_k y_k)_l ; auxSc = s.y_k ----
        float4 ha = {0.f,0.f,0.f,0.f};
        float4 aa = {0.f,0.f,0.f,0.f};
        #pragma unroll
        for (int k4 = 0; k4 < 8; ++k4) {
            const float4 t4 = *reinterpret_cast<const float4*>(sT + 4 * k4);
            const float4 s4 = *reinterpret_cast<const float4*>(sP + 4 * k4);
            const float yk0 = alpha * t4.x;
            const float yk1 = alpha * t4.y;
            const float yk2 = alpha * t4.z;
            const float yk3 = alpha * t4.w;
            g[4*k4+0] += yk0; g[4*k4+1] += yk1; g[4*k4+2] += yk2; g[4*k4+3] += yk3;
            ha.x = fmaf(hk[4*k4+0], yk0, ha.x);
            ha.y = fmaf(hk[4*k4+1], yk1, ha.y);
            ha.z = fmaf(hk[4*k4+2], yk2, ha.z);
            ha.w = fmaf(hk[4*k4+3], yk3, ha.w);
            aa.x = fmaf(s4.x, yk0, aa.x);
            aa.y = fmaf(s4.y, yk1, aa.y);
            aa.z = fmaf(s4.z, yk2, aa.z);
            aa.w = fmaf(s4.w, yk3, aa.w);
        }
        const float hy_l  = hsum4(ha);
        const float auxSc = hsum4(aa);
        sH[l] = hy_l;
        __builtin_amdgcn_wave_barrier();

        // ---- yhy = y_k . hy (replicated) ----
        float4 ya = {0.f,0.f,0.f,0.f};
        #pragma unroll
        for (int k4 = 0; k4 < 8; ++k4) {
            const float4 hy4 = *reinterpret_cast<const float4*>(sH + 4 * k4);
            const float4 t4  = *reinterpret_cast<const float4*>(sT + 4 * k4);
            ya.x = fmaf(alpha * t4.x, hy4.x, ya.x);
            ya.y = fmaf(alpha * t4.y, hy4.y, ya.y);
            ya.z = fmaf(alpha * t4.z, hy4.z, ya.z);
            ya.w = fmaf(alpha * t4.w, hy4.w, ya.w);
        }
        const float yhy = hsum4(ya);

        // ---- rank-2 h_k update:
        // hk[l][j] += (c1 s_l - hy_l/aux) * s_j  +  (-s_l/aux) * hy_j
        const float inva = 1.0f / auxSc;
        const float c1   = (auxSc + yhy) / (auxSc * auxSc);
        const float u_l  = fmaf(c1, s_l, -(hy_l * inva));
        const float w_l  = -(s_l * inva);
        #pragma unroll
        for (int k4 = 0; k4 < 8; ++k4) {
            const float4 s4  = *reinterpret_cast<const float4*>(sP + 4 * k4);
            const float4 hy4 = *reinterpret_cast<const float4*>(sH + 4 * k4);
            hk[4*k4+0] = fmaf(u_l, s4.x, fmaf(w_l, hy4.x, hk[4*k4+0]));
            hk[4*k4+1] = fmaf(u_l, s4.y, fmaf(w_l, hy4.y, hk[4*k4+1]));
            hk[4*k4+2] = fmaf(u_l, s4.z, fmaf(w_l, hy4.z, hk[4*k4+2]));
            hk[4*k4+3] = fmaf(u_l, s4.w, fmaf(w_l, hy4.w, hk[4*k4+3]));
        }
    }

    out[prob * 32 + l] = x_l;
}

extern "C" void kernel_launch(void* const* d_in, const int* in_sizes, int n_in,
                              void* d_out, int out_size, void* d_ws, size_t ws_size,
                              hipStream_t stream) {
    // inputs (setup_inputs order): y, h, x(=0, unused), alpha(=1, unused), h_k(=I, unused), iteration
    const float* y  = (const float*)d_in[0];
    const float* h  = (const float*)d_in[1];
    const int*   it = (const int*)d_in[5];
    float* out = (float*)d_out;

    const int B = in_sizes[0] / 32;            // 8192 problems
    dim3 grid(B / 8), block(256);              // 8 problems per 256-thread block
    bfgs_kernel<<<grid, block, 0, stream>>>(y, h, it, out);
}

// Round 2
// 199.846 us; speedup vs baseline: 1.0024x; 1.0024x over previous
//
#include <hip/hip_runtime.h>
#include <math.h>

#define PAD 33      // LDS stride for H: conflict-free rows AND columns
#define NBT 25      // reference MAX_BT

__device__ __forceinline__ float hsum4(float4 v) { return (v.x + v.y) + (v.z + v.w); }

// Pin occupancy to exactly 4 waves/EU (= LDS-imposed limit at 37888 B/block).
// This gives the register allocator a 128-VGPR budget so hk[32]+g[32] stay in
// registers. R1 evidence: __launch_bounds__(256,4) let the backend target
// 8 waves/EU (64 VGPRs) and spill ~650 MB/launch of scratch traffic.
__global__ __attribute__((amdgpu_flat_work_group_size(256, 256),
                          amdgpu_waves_per_eu(4, 4)))
void bfgs_kernel(
    const float* __restrict__ y_g,
    const float* __restrict__ h_g,
    const int*   __restrict__ iter_g,
    float*       __restrict__ out)
{
    // per block: 8 problems, one per 32-lane half-wave
    __shared__ __align__(16) float Hs[8][32 * PAD];   // 8 * 4224 B = 33792 B
    __shared__ __align__(16) float vs[8][4][32];      // slots: 0=p/s 1=q 2=t 3=hy (4096 B)

    const int tid  = threadIdx.x;
    const int l    = tid & 31;          // lane within problem
    const int pp   = tid >> 5;          // problem within block
    const int prob = blockIdx.x * 8 + pp;
    const int sh   = tid & 32;          // ballot shift for this half-wave

    const float* __restrict__ hb = h_g + (size_t)prob * 1024;
    float* Hp = Hs[pp];
    float* sP = vs[pp][0];
    float* sQ = vs[pp][1];
    float* sT = vs[pp][2];
    float* sH = vs[pp][3];

    // ---- stage H (row-major) into padded LDS, coalesced float4 global reads ----
    #pragma unroll
    for (int u = 0; u < 8; ++u) {
        const int f = u * 128 + l * 4;
        const float4 v = *reinterpret_cast<const float4*>(hb + f);
        const int r = f >> 5, c = f & 31;
        float* d = Hp + r * PAD + c;
        d[0] = v.x; d[1] = v.y; d[2] = v.z; d[3] = v.w;
    }
    const float yv = y_g[prob * 32 + l];
    sP[l] = yv;
    __builtin_amdgcn_wave_barrier();

    // ---- b = H^T y (distributed), c0 = y.y (replicated) ----
    float4 bacc = {0.f,0.f,0.f,0.f};
    float4 cacc = {0.f,0.f,0.f,0.f};
    #pragma unroll
    for (int k4 = 0; k4 < 8; ++k4) {
        const float4 y4 = *reinterpret_cast<const float4*>(sP + 4 * k4);
        bacc.x = fmaf(Hp[(4*k4+0)*PAD + l], y4.x, bacc.x);
        bacc.y = fmaf(Hp[(4*k4+1)*PAD + l], y4.y, bacc.y);
        bacc.z = fmaf(Hp[(4*k4+2)*PAD + l], y4.z, bacc.z);
        bacc.w = fmaf(Hp[(4*k4+3)*PAD + l], y4.w, bacc.w);
        cacc.x = fmaf(y4.x, y4.x, cacc.x);
        cacc.y = fmaf(y4.y, y4.y, cacc.y);
        cacc.z = fmaf(y4.z, y4.z, cacc.z);
        cacc.w = fmaf(y4.w, y4.w, cacc.w);
    }
    const float b_l = hsum4(bacc);
    const float c0  = hsum4(cacc);

    // allgather b -> replicated g = -b  (x0 = 0)
    sT[l] = b_l;
    __builtin_amdgcn_wave_barrier();
    float g[32];
    #pragma unroll
    for (int k4 = 0; k4 < 8; ++k4) {
        const float4 b4 = *reinterpret_cast<const float4*>(sT + 4 * k4);
        g[4*k4+0] = -b4.x; g[4*k4+1] = -b4.y; g[4*k4+2] = -b4.z; g[4*k4+3] = -b4.w;
    }

    float hk[32];                        // row l of h_k, identity init
    #pragma unroll
    for (int j = 0; j < 32; ++j) hk[j] = (j == l) ? 1.0f : 0.0f;

    float x_l = 0.0f, alpha = 1.0f, rr = c0;   // rr = ||y - H x||^2
    const int niter = iter_g[0];

    for (int it = 0; it < niter; ++it) {
        // ---- p = -(h_k @ g), all-register ----
        float4 pa = {0.f,0.f,0.f,0.f};
        #pragma unroll
        for (int k4 = 0; k4 < 8; ++k4) {
            pa.x = fmaf(hk[4*k4+0], g[4*k4+0], pa.x);
            pa.y = fmaf(hk[4*k4+1], g[4*k4+1], pa.y);
            pa.z = fmaf(hk[4*k4+2], g[4*k4+2], pa.z);
            pa.w = fmaf(hk[4*k4+3], g[4*k4+3], pa.w);
        }
        const float p_l = -hsum4(pa);
        sP[l] = p_l;
        __builtin_amdgcn_wave_barrier();

        // ---- gp = g.p (replicated) ; q_l = (H p)_l via row-l reads ----
        float4 ga = {0.f,0.f,0.f,0.f};
        float4 qa = {0.f,0.f,0.f,0.f};
        #pragma unroll
        for (int k4 = 0; k4 < 8; ++k4) {
            const float4 p4 = *reinterpret_cast<const float4*>(sP + 4 * k4);
            ga.x = fmaf(g[4*k4+0], p4.x, ga.x);
            ga.y = fmaf(g[4*k4+1], p4.y, ga.y);
            ga.z = fmaf(g[4*k4+2], p4.z, ga.z);
            ga.w = fmaf(g[4*k4+3], p4.w, ga.w);
            qa.x = fmaf(Hp[l*PAD + 4*k4+0], p4.x, qa.x);
            qa.y = fmaf(Hp[l*PAD + 4*k4+1], p4.y, qa.y);
            qa.z = fmaf(Hp[l*PAD + 4*k4+2], p4.z, qa.z);
            qa.w = fmaf(Hp[l*PAD + 4*k4+3], p4.w, qa.w);
        }
        const float gp  = hsum4(ga);
        const float q_l = hsum4(qa);
        sQ[l] = q_l;
        __builtin_amdgcn_wave_barrier();

        // ---- t_l = (H^T q)_l via column-l reads ; qq = q.q (replicated) ----
        float4 ta  = {0.f,0.f,0.f,0.f};
        float4 qqa = {0.f,0.f,0.f,0.f};
        #pragma unroll
        for (int k4 = 0; k4 < 8; ++k4) {
            const float4 q4 = *reinterpret_cast<const float4*>(sQ + 4 * k4);
            ta.x = fmaf(Hp[(4*k4+0)*PAD + l], q4.x, ta.x);
            ta.y = fmaf(Hp[(4*k4+1)*PAD + l], q4.y, ta.y);
            ta.z = fmaf(Hp[(4*k4+2)*PAD + l], q4.z, ta.z);
            ta.w = fmaf(Hp[(4*k4+3)*PAD + l], q4.w, ta.w);
            qqa.x = fmaf(q4.x, q4.x, qqa.x);
            qqa.y = fmaf(q4.y, q4.y, qqa.y);
            qqa.z = fmaf(q4.z, q4.z, qqa.z);
            qqa.w = fmaf(q4.w, q4.w, qqa.w);
        }
        const float t_l = hsum4(ta);
        const float qq  = hsum4(qqa);

        // ---- Armijo backtracking, ballot-parallel over candidate alphas ----
        // phi(a) = ||r - a q||^2 = rr - 2 a rq + a^2 qq,  rq = r.q = -g.p
        // cond(a) = f(x+ap) > fx + C a gp  <=>  rhs<0 || phi/4 > rhs^2
        const float rq = -gp;
        const float fx = 0.5f * sqrtf(rr);
        const float a_c = ldexpf(alpha, -l);            // exact: alpha * 2^-l
        const float rhs = fx + (1e-4f * a_c) * gp;
        const float phi_c = fmaf(a_c, fmaf(a_c, qq, -2.0f * rq), rr);
        const bool cond = (rhs < 0.0f) || (0.25f * phi_c > rhs * rhs);
        const unsigned long long bal = __ballot(cond);
        const unsigned mh  = (unsigned)(bal >> sh);
        const unsigned inv = (~mh & 0x01FFFFFFu) | 0x02000000u; // first false idx, cap 25
        const int kk = __ffs(inv) - 1;
        alpha = ldexpf(alpha, -kk);

        // ---- x update; s with the reference's rounding (x_new - x) ----
        const float xn  = fmaf(alpha, p_l, x_l);
        const float s_l = xn - x_l;
        x_l = xn;
        rr = fmaf(alpha, fmaf(alpha, qq, -2.0f * rq), rr);   // rr at accepted alpha

        sP[l] = s_l;     // overwrite p slot (p fully consumed)
        sT[l] = t_l;
        __builtin_amdgcn_wave_barrier();

        // ---- fused: g += alpha*t ; hy_l = (h_k y_k)_l ; auxSc = s.y_k ----
        float4 ha = {0.f,0.f,0.f,0.f};
        float4 aa = {0.f,0.f,0.f,0.f};
        #pragma unroll
        for (int k4 = 0; k4 < 8; ++k4) {
            const float4 t4 = *reinterpret_cast<const float4*>(sT + 4 * k4);
            const float4 s4 = *reinterpret_cast<const float4*>(sP + 4 * k4);
            const float yk0 = alpha * t4.x;
            const float yk1 = alpha * t4.y;
            const float yk2 = alpha * t4.z;
            const float yk3 = alpha * t4.w;
            g[4*k4+0] += yk0; g[4*k4+1] += yk1; g[4*k4+2] += yk2; g[4*k4+3] += yk3;
            ha.x = fmaf(hk[4*k4+0], yk0, ha.x);
            ha.y = fmaf(hk[4*k4+1], yk1, ha.y);
            ha.z = fmaf(hk[4*k4+2], yk2, ha.z);
            ha.w = fmaf(hk[4*k4+3], yk3, ha.w);
            aa.x = fmaf(s4.x, yk0, aa.x);
            aa.y = fmaf(s4.y, yk1, aa.y);
            aa.z = fmaf(s4.z, yk2, aa.z);
            aa.w = fmaf(s4.w, yk3, aa.w);
        }
        const float hy_l  = hsum4(ha);
        const float auxSc = hsum4(aa);
        sH[l] = hy_l;
        __builtin_amdgcn_wave_barrier();

        // ---- yhy = y_k . hy (replicated) ----
        float4 ya = {0.f,0.f,0.f,0.f};
        #pragma unroll
        for (int k4 = 0; k4 < 8; ++k4) {
            const float4 hy4 = *reinterpret_cast<const float4*>(sH + 4 * k4);
            const float4 t4  = *reinterpret_cast<const float4*>(sT + 4 * k4);
            ya.x = fmaf(alpha * t4.x, hy4.x, ya.x);
            ya.y = fmaf(alpha * t4.y, hy4.y, ya.y);
            ya.z = fmaf(alpha * t4.z, hy4.z, ya.z);
            ya.w = fmaf(alpha * t4.w, hy4.w, ya.w);
        }
        const float yhy = hsum4(ya);

        // ---- rank-2 h_k update:
        // hk[l][j] += (c1 s_l - hy_l/aux) * s_j  +  (-s_l/aux) * hy_j
        const float inva = 1.0f / auxSc;
        const float c1   = (auxSc + yhy) / (auxSc * auxSc);
        const float u_l  = fmaf(c1, s_l, -(hy_l * inva));
        const float w_l  = -(s_l * inva);
        #pragma unroll
        for (int k4 = 0; k4 < 8; ++k4) {
            const float4 s4  = *reinterpret_cast<const float4*>(sP + 4 * k4);
            const float4 hy4 = *reinterpret_cast<const float4*>(sH + 4 * k4);
            hk[4*k4+0] = fmaf(u_l, s4.x, fmaf(w_l, hy4.x, hk[4*k4+0]));
            hk[4*k4+1] = fmaf(u_l, s4.y, fmaf(w_l, hy4.y, hk[4*k4+1]));
            hk[4*k4+2] = fmaf(u_l, s4.z, fmaf(w_l, hy4.z, hk[4*k4+2]));
            hk[4*k4+3] = fmaf(u_l, s4.w, fmaf(w_l, hy4.w, hk[4*k4+3]));
        }
    }

    out[prob * 32 + l] = x_l;
}

extern "C" void kernel_launch(void* const* d_in, const int* in_sizes, int n_in,
                              void* d_out, int out_size, void* d_ws, size_t ws_size,
                              hipStream_t stream) {
    // inputs (setup_inputs order): y, h, x(=0, unused), alpha(=1, unused), h_k(=I, unused), iteration
    const float* y  = (const float*)d_in[0];
    const float* h  = (const float*)d_in[1];
    const int*   it = (const int*)d_in[5];
    float* out = (float*)d_out;

    const int B = in_sizes[0] / 32;            // 8192 problems
    dim3 grid(B / 8), block(256);              // 8 problems per 256-thread block
    bfgs_kernel<<<grid, block, 0, stream>>>(y, h, it, out);
}

// Round 3
// 45.773 us; speedup vs baseline: 4.3766x; 4.3660x over previous
//
#include <hip/hip_runtime.h>
#include <math.h>

#define PAD 33      // LDS stride for H: conflict-free rows AND columns

__device__ __forceinline__ float hsum4(float4 v) { return (v.x + v.y) + (v.z + v.w); }

// butterfly sum over the 32-lane half-wave (masks <32 stay within the group)
__device__ __forceinline__ float red32(float v) {
    v += __shfl_xor(v, 1);
    v += __shfl_xor(v, 2);
    v += __shfl_xor(v, 4);
    v += __shfl_xor(v, 8);
    v += __shfl_xor(v, 16);
    return v;
}

// R2 lesson: the allocator pins 64 VGPRs regardless of waves_per_eu hints, so
// the kernel is restructured to FIT 64: hk[32] is the only register array;
// g is distributed (lane l holds g_l) and vectors are broadcast from LDS.
__global__ __launch_bounds__(256, 4) void bfgs_kernel(
    const float* __restrict__ y_g,
    const float* __restrict__ h_g,
    const int*   __restrict__ iter_g,
    float*       __restrict__ out)
{
    // per block: 8 problems, one per 32-lane half-wave
    __shared__ __align__(16) float Hs[8][32 * PAD];   // 8 * 4224 B = 33792 B
    __shared__ __align__(16) float vs[8][5][32];      // 0=G 1=P(s) 2=Q 3=T(yk) 4=H(hy)

    const int tid  = threadIdx.x;
    const int l    = tid & 31;          // lane within problem
    const int pp   = tid >> 5;          // problem within block
    const int prob = blockIdx.x * 8 + pp;
    const int sh   = tid & 32;          // ballot shift for this half-wave

    const float* __restrict__ hb = h_g + (size_t)prob * 1024;
    float* Hp = Hs[pp];
    float* sG = vs[pp][0];
    float* sP = vs[pp][1];
    float* sQ = vs[pp][2];
    float* sT = vs[pp][3];
    float* sH = vs[pp][4];

    // ---- stage H (row-major) into padded LDS, coalesced float4 global reads ----
    #pragma unroll
    for (int u = 0; u < 8; ++u) {
        const int f = u * 128 + l * 4;
        const float4 v = *reinterpret_cast<const float4*>(hb + f);
        const int r = f >> 5, c = f & 31;
        float* d = Hp + r * PAD + c;
        d[0] = v.x; d[1] = v.y; d[2] = v.z; d[3] = v.w;
    }
    const float yv = y_g[prob * 32 + l];
    sQ[l] = yv;                              // Q slot temporarily holds y
    __builtin_amdgcn_wave_barrier();

    // ---- g_l = -(H^T y)_l via column-l reads ; rr = ||y||^2 (x0 = 0) ----
    float4 ba = {0.f,0.f,0.f,0.f};
    #pragma unroll
    for (int k4 = 0; k4 < 8; ++k4) {
        const float4 y4 = *reinterpret_cast<const float4*>(sQ + 4 * k4);
        ba.x = fmaf(Hp[(4*k4+0)*PAD + l], y4.x, ba.x);
        ba.y = fmaf(Hp[(4*k4+1)*PAD + l], y4.y, ba.y);
        ba.z = fmaf(Hp[(4*k4+2)*PAD + l], y4.z, ba.z);
        ba.w = fmaf(Hp[(4*k4+3)*PAD + l], y4.w, ba.w);
    }
    float g_l = -hsum4(ba);
    float rr  = red32(yv * yv);              // ||y - H*0||^2
    sG[l] = g_l;
    __builtin_amdgcn_wave_barrier();

    float hk[32];                            // row l of h_k, identity init
    #pragma unroll
    for (int j = 0; j < 32; ++j) hk[j] = (j == l) ? 1.0f : 0.0f;

    float x_l = 0.0f, alpha = 1.0f;
    const int niter = iter_g[0];

    for (int it = 0; it < niter; ++it) {
        // ---- p_l = -(h_k @ g)_l : hk row (regs) x g (LDS broadcast) ----
        float4 pa = {0.f,0.f,0.f,0.f};
        #pragma unroll
        for (int k4 = 0; k4 < 8; ++k4) {
            const float4 g4 = *reinterpret_cast<const float4*>(sG + 4 * k4);
            pa.x = fmaf(hk[4*k4+0], g4.x, pa.x);
            pa.y = fmaf(hk[4*k4+1], g4.y, pa.y);
            pa.z = fmaf(hk[4*k4+2], g4.z, pa.z);
            pa.w = fmaf(hk[4*k4+3], g4.w, pa.w);
        }
        const float p_l = -hsum4(pa);
        const float gp  = red32(g_l * p_l);          // g.p
        sP[l] = p_l;
        __builtin_amdgcn_wave_barrier();

        // ---- q_l = (H p)_l via row-l reads ; qq = q.q ----
        float4 qa = {0.f,0.f,0.f,0.f};
        #pragma unroll
        for (int k4 = 0; k4 < 8; ++k4) {
            const float4 p4 = *reinterpret_cast<const float4*>(sP + 4 * k4);
            qa.x = fmaf(Hp[l*PAD + 4*k4+0], p4.x, qa.x);
            qa.y = fmaf(Hp[l*PAD + 4*k4+1], p4.y, qa.y);
            qa.z = fmaf(Hp[l*PAD + 4*k4+2], p4.z, qa.z);
            qa.w = fmaf(Hp[l*PAD + 4*k4+3], p4.w, qa.w);
        }
        const float q_l = hsum4(qa);
        const float qq  = red32(q_l * q_l);
        sQ[l] = q_l;
        __builtin_amdgcn_wave_barrier();

        // ---- t_l = (H^T q)_l via column-l reads ----
        float4 ta = {0.f,0.f,0.f,0.f};
        #pragma unroll
        for (int k4 = 0; k4 < 8; ++k4) {
            const float4 q4 = *reinterpret_cast<const float4*>(sQ + 4 * k4);
            ta.x = fmaf(Hp[(4*k4+0)*PAD + l], q4.x, ta.x);
            ta.y = fmaf(Hp[(4*k4+1)*PAD + l], q4.y, ta.y);
            ta.z = fmaf(Hp[(4*k4+2)*PAD + l], q4.z, ta.z);
            ta.w = fmaf(Hp[(4*k4+3)*PAD + l], q4.w, ta.w);
        }
        const float t_l = hsum4(ta);

        // ---- Armijo backtracking, ballot-parallel over candidate alphas ----
        // phi(a) = rr - 2 a rq + a^2 qq,  rq = r.q = -g.p
        // cond(a) = f(x+ap) > fx + C a gp  <=>  rhs<0 || phi/4 > rhs^2
        const float rq = -gp;
        const float fx = 0.5f * sqrtf(rr);
        const float a_c = ldexpf(alpha, -l);            // exact: alpha * 2^-l
        const float rhs = fx + (1e-4f * a_c) * gp;
        const float phi_c = fmaf(a_c, fmaf(a_c, qq, -2.0f * rq), rr);
        const bool cond = (rhs < 0.0f) || (0.25f * phi_c > rhs * rhs);
        const unsigned long long bal = __ballot(cond);
        const unsigned mh  = (unsigned)(bal >> sh);
        const unsigned inv = (~mh & 0x01FFFFFFu) | 0x02000000u; // first false idx, cap 25
        const int kk = __ffs(inv) - 1;
        alpha = ldexpf(alpha, -kk);

        // ---- x update; s with the reference's rounding (x_new - x) ----
        const float xn  = fmaf(alpha, p_l, x_l);
        const float s_l = xn - x_l;
        x_l = xn;
        rr = fmaf(alpha, fmaf(alpha, qq, -2.0f * rq), rr);   // rr at accepted alpha

        // ---- y_k = alpha * t (distributed); g += y_k; auxSc = s.y_k ----
        const float yk_l = alpha * t_l;
        g_l += yk_l;
        const float auxSc = red32(s_l * yk_l);
        sP[l] = s_l;          // overwrite p slot (p fully consumed)
        sT[l] = yk_l;
        sG[l] = g_l;
        __builtin_amdgcn_wave_barrier();

        // ---- hy_l = (h_k y_k)_l : hk row x yk (broadcast) ; yhy = yk.hy ----
        float4 ha = {0.f,0.f,0.f,0.f};
        #pragma unroll
        for (int k4 = 0; k4 < 8; ++k4) {
            const float4 yk4 = *reinterpret_cast<const float4*>(sT + 4 * k4);
            ha.x = fmaf(hk[4*k4+0], yk4.x, ha.x);
            ha.y = fmaf(hk[4*k4+1], yk4.y, ha.y);
            ha.z = fmaf(hk[4*k4+2], yk4.z, ha.z);
            ha.w = fmaf(hk[4*k4+3], yk4.w, ha.w);
        }
        const float hy_l = hsum4(ha);
        const float yhy  = red32(yk_l * hy_l);
        sH[l] = hy_l;
        __builtin_amdgcn_wave_barrier();

        // ---- rank-2 h_k update:
        // hk[l][j] += (c1 s_l - hy_l/aux) * s_j  +  (-s_l/aux) * hy_j
        const float inva = 1.0f / auxSc;
        const float c1   = (auxSc + yhy) * (inva * inva);
        const float u_l  = fmaf(c1, s_l, -(hy_l * inva));
        const float w_l  = -(s_l * inva);
        #pragma unroll
        for (int k4 = 0; k4 < 8; ++k4) {
            const float4 s4  = *reinterpret_cast<const float4*>(sP + 4 * k4);
            const float4 hy4 = *reinterpret_cast<const float4*>(sH + 4 * k4);
            hk[4*k4+0] = fmaf(u_l, s4.x, fmaf(w_l, hy4.x, hk[4*k4+0]));
            hk[4*k4+1] = fmaf(u_l, s4.y, fmaf(w_l, hy4.y, hk[4*k4+1]));
            hk[4*k4+2] = fmaf(u_l, s4.z, fmaf(w_l, hy4.z, hk[4*k4+2]));
            hk[4*k4+3] = fmaf(u_l, s4.w, fmaf(w_l, hy4.w, hk[4*k4+3]));
        }
    }

    out[prob * 32 + l] = x_l;
}

extern "C" void kernel_launch(void* const* d_in, const int* in_sizes, int n_in,
                              void* d_out, int out_size, void* d_ws, size_t ws_size,
                              hipStream_t stream) {
    // inputs (setup_inputs order): y, h, x(=0, unused), alpha(=1, unused), h_k(=I, unused), iteration
    const float* y  = (const float*)d_in[0];
    const float* h  = (const float*)d_in[1];
    const int*   it = (const int*)d_in[5];
    float* out = (float*)d_out;

    const int B = in_sizes[0] / 32;            // 8192 problems
    dim3 grid(B / 8), block(256);              // 8 problems per 256-thread block
    bfgs_kernel<<<grid, block, 0, stream>>>(y, h, it, out);
}